// Round 8
// baseline (137.909 us; speedup 1.0000x reference)
//
#include <hip/hip_runtime.h>

typedef __bf16 bf16x8 __attribute__((ext_vector_type(8)));
typedef float  f32x4  __attribute__((ext_vector_type(4)));
typedef unsigned short u16x8 __attribute__((ext_vector_type(8)));

#define NB 1024
#define NN 128
#define NH 64
#define NOUT 128

__device__ __forceinline__ unsigned short f2b(float f) {
    return __builtin_bit_cast(unsigned short, (__bf16)f);
}

// ---------------- K1: adj fp32 -> bf16 pre-swizzled LDS images in ws ---------
__global__ __launch_bounds__(256)
void convert_adj(const float* __restrict__ adj, char* __restrict__ ws)
{
    const int g = blockIdx.x * 256 + threadIdx.x;
    #pragma unroll 4
    for (int it = 0; it < 4; ++it) {
        int flat8 = it * 524288 + g;
        const float4* s = (const float4*)adj + (size_t)flat8 * 2;
        float4 a = s[0], c = s[1];
        int b   = flat8 >> 11;
        int rem = flat8 & 2047;
        int i   = rem >> 4;
        int jb  = (rem & 15) * 16;
        u16x8 u;
        u[0]=f2b(a.x); u[1]=f2b(a.y); u[2]=f2b(a.z); u[3]=f2b(a.w);
        u[4]=f2b(c.x); u[5]=f2b(c.y); u[6]=f2b(c.z); u[7]=f2b(c.w);
        *(u16x8*)(ws + (size_t)b * 32768 + i * 256 + (jb ^ ((i & 7) << 4))) = u;
    }
}

__device__ __forceinline__ void gload_lds16(const void* g, void* l) {
    __builtin_amdgcn_global_load_lds(
        (const __attribute__((address_space(1))) unsigned int*)g,
        (__attribute__((address_space(3))) unsigned int*)l, 16, 0, 0);
}

// ================= shared K2 building blocks (r5/r7-validated math) ==========
__device__ __forceinline__ void stage_embed(int b, int t,
    const char* __restrict__ ws, const int* __restrict__ graph,
    const float* __restrict__ embed, char* adj_s, char* hT_s)
{
    const int lane = t & 63;
    const int wv   = t >> 6;
    const char* wsb = ws + (size_t)b * 32768;
    #pragma unroll
    for (int q = 0; q < 4; ++q) {
        int chunk = (wv * 4 + q) * 1024;
        gload_lds16(wsb + chunk + lane * 16, adj_s + chunk);
    }
    const int jq = t & 31;
    const int d0 = (t >> 5) * 4;
    const int4 g4 = *(const int4*)(graph + b * NN + jq * 4);
    float ea[4][4];
    *(float4*)ea[0] = *(const float4*)(embed + g4.x * NH + d0);
    *(float4*)ea[1] = *(const float4*)(embed + g4.y * NH + d0);
    *(float4*)ea[2] = *(const float4*)(embed + g4.z * NH + d0);
    *(float4*)ea[3] = *(const float4*)(embed + g4.w * NH + d0);
    #pragma unroll
    for (int k = 0; k < 4; ++k) {
        int d = d0 + k;
        ushort4 u;
        u.x = f2b(ea[0][k]); u.y = f2b(ea[1][k]);
        u.z = f2b(ea[2][k]); u.w = f2b(ea[3][k]);
        *(ushort4*)(hT_s + d * 256 + ((jq * 8) ^ ((d & 7) << 4))) = u;
    }
}

__device__ __forceinline__ void load_wf(const float* __restrict__ W,
                                        int l15, int lg, bf16x8* wf)
{
    #pragma unroll
    for (int nt = 0; nt < 4; ++nt)
        #pragma unroll
        for (int kk = 0; kk < 2; ++kk) {
            const float4* p = (const float4*)(W + (nt * 16 + l15) * NH + kk * 32 + lg * 8);
            float4 v0 = p[0], v1 = p[1];
            bf16x8 a;
            a[0] = (__bf16)v0.x; a[1] = (__bf16)v0.y; a[2] = (__bf16)v0.z; a[3] = (__bf16)v0.w;
            a[4] = (__bf16)v1.x; a[5] = (__bf16)v1.y; a[6] = (__bf16)v1.z; a[7] = (__bf16)v1.w;
            wf[nt * 2 + kk] = a;
        }
}

__device__ __forceinline__ void do_matA(int wv, int l15, int lg,
    const char* adj_s, const char* hT_s, char* S_s)
{
    const int mtA  = wv & 3;
    const int ntA0 = (wv >> 2) * 4;
    f32x4 acc[4] = {};
    const int arow = mtA * 16 + l15;
    const int koff = lg * 16;
    #pragma unroll
    for (int kk = 0; kk < 4; ++kk) {
        int kb = kk * 64 + koff;
        bf16x8 af = *(const bf16x8*)(hT_s + arow * 256 + (kb ^ ((arow & 7) << 4)));
        #pragma unroll
        for (int nt = 0; nt < 4; ++nt) {
            int brow = (ntA0 + nt) * 16 + l15;
            bf16x8 bfr = *(const bf16x8*)(adj_s + brow * 256 + (kb ^ ((brow & 7) << 4)));
            acc[nt] = __builtin_amdgcn_mfma_f32_16x16x32_bf16(af, bfr, acc[nt], 0, 0, 0);
        }
    }
    const int dd0 = mtA * 16 + lg * 4;
    #pragma unroll
    for (int nt = 0; nt < 4; ++nt) {
        int node = (ntA0 + nt) * 16 + l15;
        ushort4 u;
        u.x = f2b(acc[nt][0]); u.y = f2b(acc[nt][1]);
        u.z = f2b(acc[nt][2]); u.w = f2b(acc[nt][3]);
        *(ushort4*)(S_s + node * 128 + ((dd0 * 2) ^ ((node & 7) << 4))) = u;
    }
}

__device__ __forceinline__ void do_matB(int wv, int l15, int lg,
    const char* S_s, const bf16x8* wf, char* hT_s)
{
    f32x4 acc[4] = {};
    const int arow = wv * 16 + l15;
    const int koff = lg * 16;
    #pragma unroll
    for (int kk = 0; kk < 2; ++kk) {
        int kb = kk * 64 + koff;
        bf16x8 af = *(const bf16x8*)(S_s + arow * 128 + (kb ^ ((arow & 7) << 4)));
        #pragma unroll
        for (int nt = 0; nt < 4; ++nt)
            acc[nt] = __builtin_amdgcn_mfma_f32_16x16x32_bf16(af, wf[nt * 2 + kk],
                                                              acc[nt], 0, 0, 0);
    }
    const int node0 = wv * 16 + lg * 4;
    #pragma unroll
    for (int nt = 0; nt < 4; ++nt) {
        int dout = nt * 16 + l15;
        ushort4 u;
        u.x = f2b(fmaxf(acc[nt][0], 0.f)); u.y = f2b(fmaxf(acc[nt][1], 0.f));
        u.z = f2b(fmaxf(acc[nt][2], 0.f)); u.w = f2b(fmaxf(acc[nt][3], 0.f));
        *(ushort4*)(hT_s + dout * 256 + ((node0 * 2) ^ ((dout & 7) << 4))) = u;
    }
}

__device__ __forceinline__ void layer3_out(int b, int t,
    const char* adj_s, const char* hT_s, char* S_s,
    const float* __restrict__ W3, float* __restrict__ outp)
{
    const int lane = t & 63;
    const int wv   = t >> 6;
    const int l15  = lane & 15;
    const int lg   = lane >> 4;
    float* const svecp = (float*)S_s;
    float* const svec  = (float*)(S_s + 2048);
    {
        f32x4 acc3[4] = {};
        const int koff = lg * 16;
        const int brow = wv * 16 + l15;
        #pragma unroll
        for (int kk = 0; kk < 4; ++kk) {
            int kb = kk * 64 + koff;
            bf16x8 bfr = *(const bf16x8*)(adj_s + brow * 256 + (kb ^ ((brow & 7) << 4)));
            #pragma unroll
            for (int dt = 0; dt < 4; ++dt) {
                int arow = dt * 16 + l15;
                bf16x8 ha = *(const bf16x8*)(hT_s + arow * 256 + (kb ^ ((arow & 7) << 4)));
                acc3[dt] = __builtin_amdgcn_mfma_f32_16x16x32_bf16(ha, bfr, acc3[dt], 0, 0, 0);
            }
        }
        #pragma unroll
        for (int m = 1; m <= 8; m <<= 1)
            #pragma unroll
            for (int dt = 0; dt < 4; ++dt)
                #pragma unroll
                for (int i = 0; i < 4; ++i)
                    acc3[dt][i] += __shfl_xor(acc3[dt][i], m);
        if (l15 == 0) {
            #pragma unroll
            for (int dt = 0; dt < 4; ++dt)
                *(f32x4*)(svecp + wv * 64 + dt * 16 + lg * 4) = acc3[dt];
        }
    }
    __syncthreads();
    if (t < 64) {
        float s = 0.f;
        #pragma unroll
        for (int w = 0; w < 8; ++w) s += svecp[w * 64 + t];
        svec[t] = s;
    }
    __syncthreads();
    if (t < 128) {
        const float4* wrow = (const float4*)(W3 + t * NH);
        float a0 = 0.f, a1 = 0.f;
        #pragma unroll
        for (int q = 0; q < 16; q += 2) {
            float4 w0 = wrow[q], w1 = wrow[q + 1];
            a0 += w0.x*svec[q*4+0] + w0.y*svec[q*4+1] + w0.z*svec[q*4+2] + w0.w*svec[q*4+3];
            a1 += w1.x*svec[q*4+4] + w1.y*svec[q*4+5] + w1.z*svec[q*4+6] + w1.w*svec[q*4+7];
        }
        outp[b * NOUT + t] = a0 + a1;
    }
}

__device__ __forceinline__ void gcn_full_body(int b, int t,
    const char* __restrict__ ws, const int* __restrict__ graph,
    const float* __restrict__ embed, const float* __restrict__ W1,
    const float* __restrict__ W2, const float* __restrict__ W3,
    float* __restrict__ outp, char* adj_s, char* hT_s, char* S_s)
{
    const int lane = t & 63;
    const int wv   = t >> 6;
    const int l15  = lane & 15;
    const int lg   = lane >> 4;
    stage_embed(b, t, ws, graph, embed, adj_s, hT_s);
    __syncthreads();
    #pragma unroll
    for (int layer = 0; layer < 2; ++layer) {
        const float* W = layer ? W2 : W1;
        bf16x8 wf[8];
        load_wf(W, l15, lg, wf);
        do_matA(wv, l15, lg, adj_s, hT_s, S_s);
        __syncthreads();
        do_matB(wv, l15, lg, S_s, wf, hT_s);
        __syncthreads();
    }
    layer3_out(b, t, adj_s, hT_s, S_s, W3, outp);
}

// ================= ablation suite =============================================
// V_stage: staging+embed only, checksum keeps LDS live.
__global__ __launch_bounds__(512, 4)
void k2_stageonly(const int* __restrict__ graph, const char* __restrict__ ws,
                  const float* __restrict__ embed, float* __restrict__ chk)
{
    __shared__ __align__(16) char smem[65536];
    const int b = blockIdx.x, t = threadIdx.x;
    stage_embed(b, t, ws, graph, embed, smem, smem + 32768);
    __syncthreads();
    u16x8 a = *(const u16x8*)(smem + t * 64);
    u16x8 h = *(const u16x8*)(smem + 32768 + t * 32);
    float s = 0.f;
    #pragma unroll
    for (int j = 0; j < 8; ++j) s += (float)a[j] + (float)h[j];
    chk[b * 512 + t] = s;
}

// V_1layer: staging + one matA + one matB, checksum of S and hT.
__global__ __launch_bounds__(512, 4)
void k2_onelayer(const int* __restrict__ graph, const char* __restrict__ ws,
                 const float* __restrict__ embed, const float* __restrict__ W1,
                 float* __restrict__ chk)
{
    __shared__ __align__(16) char smem[65536];
    char* const adj_s = smem;
    char* const hT_s  = smem + 32768;
    char* const S_s   = smem + 49152;
    const int b = blockIdx.x, t = threadIdx.x;
    const int lane = t & 63, wv = t >> 6, l15 = lane & 15, lg = lane >> 4;
    stage_embed(b, t, ws, graph, embed, adj_s, hT_s);
    __syncthreads();
    bf16x8 wf[8];
    load_wf(W1, l15, lg, wf);
    do_matA(wv, l15, lg, adj_s, hT_s, S_s);
    __syncthreads();
    do_matB(wv, l15, lg, S_s, wf, hT_s);
    __syncthreads();
    u16x8 sS = *(const u16x8*)(S_s + t * 32);
    u16x8 sH = *(const u16x8*)(hT_s + t * 32);
    float s = 0.f;
    #pragma unroll
    for (int j = 0; j < 8; ++j) s += (float)sS[j] + (float)sH[j];
    chk[b * 512 + t] = s;
}

// V_full_nb: full pipeline, NO min-waves bound (allocator free), dummy out.
__global__ __launch_bounds__(512)
void k2_full_nb(const int* __restrict__ graph, const char* __restrict__ ws,
                const float* __restrict__ embed, const float* __restrict__ W1,
                const float* __restrict__ W2, const float* __restrict__ W3,
                float* __restrict__ outp)
{
    __shared__ __align__(16) char smem[65536];
    gcn_full_body(blockIdx.x, threadIdx.x, ws, graph, embed, W1, W2, W3, outp,
                  smem, smem + 32768, smem + 49152);
}

// V_full_b4: full pipeline, current (512,4) bounds, real output.
__global__ __launch_bounds__(512, 4)
void k2_full_b4(const int* __restrict__ graph, const char* __restrict__ ws,
                const float* __restrict__ embed, const float* __restrict__ W1,
                const float* __restrict__ W2, const float* __restrict__ W3,
                float* __restrict__ outp)
{
    __shared__ __align__(16) char smem[65536];
    gcn_full_body(blockIdx.x, threadIdx.x, ws, graph, embed, W1, W2, W3, outp,
                  smem, smem + 32768, smem + 49152);
}

extern "C" void kernel_launch(void* const* d_in, const int* in_sizes, int n_in,
                              void* d_out, int out_size, void* d_ws, size_t ws_size,
                              hipStream_t stream) {
    const int*   graph = (const int*)d_in[0];
    const float* adjp  = (const float*)d_in[1];
    const float* embed = (const float*)d_in[2];
    const float* W1    = (const float*)d_in[3];
    const float* W2    = (const float*)d_in[4];
    const float* W3    = (const float*)d_in[5];
    float* outp = (float*)d_out;
    char*  wsb  = (char*)d_ws;

    char*  img   = wsb;                                  // 32 MiB image
    float* chk0  = (float*)(wsb + (size_t)48 * 1024 * 1024);   // 2 MiB
    float* chk1  = (float*)(wsb + (size_t)56 * 1024 * 1024);   // 2 MiB
    float* dummy = (float*)(wsb + (size_t)64 * 1024 * 1024);   // 512 KiB

    convert_adj <<<dim3(2048), dim3(256), 0, stream>>>(adjp, img);
    k2_stageonly<<<dim3(NB),   dim3(512), 0, stream>>>(graph, img, embed, chk0);
    k2_onelayer <<<dim3(NB),   dim3(512), 0, stream>>>(graph, img, embed, W1, chk1);
    k2_full_nb  <<<dim3(NB),   dim3(512), 0, stream>>>(graph, img, embed, W1, W2, W3, dummy);
    k2_full_b4  <<<dim3(NB),   dim3(512), 0, stream>>>(graph, img, embed, W1, W2, W3, outp);
}

// Round 9
// 36.801 us; speedup vs baseline: 3.7474x; 3.7474x over previous
//
#include <hip/hip_runtime.h>

typedef __bf16 bf16x8 __attribute__((ext_vector_type(8)));
typedef float  f32x4  __attribute__((ext_vector_type(4)));

#define NB 1024
#define NN 128
#define NH 64
#define NOUT 128

__device__ __forceinline__ unsigned short f2b(float f) {
    return __builtin_bit_cast(unsigned short, (__bf16)f);
}

// One block per batch, 256 threads = 4 waves, (256,2): VGPR budget 256, 2 blocks/CU.
// LDS: adj[128][256B] bf16 | hT[64][256B] d-major | S[128][128B]; XOR swizzle
// byte ^= (row&7)<<4 on all three. Phases issue ALL ds_reads before the MFMA
// cluster (m97 shape) so the compiler emits staged lgkmcnt, not per-read drains.
__global__ __launch_bounds__(256, 2)
void rsgcn_fused(const int* __restrict__ graph, const float* __restrict__ adj,
                 const float* __restrict__ embed, const float* __restrict__ W1,
                 const float* __restrict__ W2, const float* __restrict__ W3,
                 float* __restrict__ out)
{
    __shared__ __align__(16) char smem[65536];
    char* const adj_s = smem;           // 32768 B
    char* const hT_s  = smem + 32768;   // 16384 B
    char* const S_s   = smem + 49152;   // 16384 B
    float* const svec = (float*)S_s;    // [64] overlay (S dead in epilogue)

    const int b    = blockIdx.x;
    const int t    = threadIdx.x;
    const int lane = t & 63;
    const int wv   = t >> 6;
    const int l15  = lane & 15;
    const int lg   = lane >> 4;

    // ---------------- stage adj: fp32 -> bf16 swizzled LDS (r2-verified) -----
    const float4* adj4 = (const float4*)(adj + (size_t)b * (NN * NN));
    #pragma unroll
    for (int i = 0; i < 16; ++i) {
        int fi = i * 256 + t;
        float4 v = adj4[fi];
        int row  = fi >> 5;
        int colb = (fi & 31) * 8;
        ushort4 u;
        u.x = f2b(v.x); u.y = f2b(v.y); u.z = f2b(v.z); u.w = f2b(v.w);
        *(ushort4*)(adj_s + row * 256 + (colb ^ ((row & 7) << 4))) = u;
    }

    // ---------------- embed gather -> hT (r5-verified packed writes) ---------
    {
        const int jq = t & 31;            // nodes 4*jq..+3
        const int d0 = (t >> 5) * 8;      // 8 features per thread
        const int4 g4 = *(const int4*)(graph + b * NN + jq * 4);
        float ea[4][8];
        *(float4*)&ea[0][0] = *(const float4*)(embed + g4.x * NH + d0);
        *(float4*)&ea[0][4] = *(const float4*)(embed + g4.x * NH + d0 + 4);
        *(float4*)&ea[1][0] = *(const float4*)(embed + g4.y * NH + d0);
        *(float4*)&ea[1][4] = *(const float4*)(embed + g4.y * NH + d0 + 4);
        *(float4*)&ea[2][0] = *(const float4*)(embed + g4.z * NH + d0);
        *(float4*)&ea[2][4] = *(const float4*)(embed + g4.z * NH + d0 + 4);
        *(float4*)&ea[3][0] = *(const float4*)(embed + g4.w * NH + d0);
        *(float4*)&ea[3][4] = *(const float4*)(embed + g4.w * NH + d0 + 4);
        #pragma unroll
        for (int k = 0; k < 8; ++k) {
            int d = d0 + k;
            ushort4 u;
            u.x = f2b(ea[0][k]); u.y = f2b(ea[1][k]);
            u.z = f2b(ea[2][k]); u.w = f2b(ea[3][k]);
            *(ushort4*)(hT_s + d * 256 + ((jq * 8) ^ ((d & 7) << 4))) = u;
        }
    }
    __syncthreads();

    // ---------------- layers 1,2: h' = relu((adj @ h) @ W^T) -----------------
    #pragma unroll
    for (int layer = 0; layer < 2; ++layer) {
        const float* W = layer ? W2 : W1;

        // ---- matA: S^T[d][node]; wave wv owns d-tile wv, all 8 node tiles ---
        {
            f32x4 acc[8] = {};
            const int arow = wv * 16 + l15;          // hT row (d)
            #pragma unroll
            for (int kk = 0; kk < 4; ++kk) {
                const int kb = kk * 64 + lg * 16;
                // batch: 9 ds_read_b128, no interleaved consumers
                bf16x8 af = *(const bf16x8*)(hT_s + arow * 256 + (kb ^ ((arow & 7) << 4)));
                bf16x8 bfr[8];
                #pragma unroll
                for (int nt = 0; nt < 8; ++nt) {
                    int brow = nt * 16 + l15;
                    bfr[nt] = *(const bf16x8*)(adj_s + brow * 256 + (kb ^ ((brow & 7) << 4)));
                }
                // cluster: 8 MFMAs
                #pragma unroll
                for (int nt = 0; nt < 8; ++nt)
                    acc[nt] = __builtin_amdgcn_mfma_f32_16x16x32_bf16(af, bfr[nt], acc[nt], 0, 0, 0);
            }
            const int dd0 = wv * 16 + lg * 4;
            #pragma unroll
            for (int nt = 0; nt < 8; ++nt) {
                int node = nt * 16 + l15;
                ushort4 u;
                u.x = f2b(acc[nt][0]); u.y = f2b(acc[nt][1]);
                u.z = f2b(acc[nt][2]); u.w = f2b(acc[nt][3]);
                *(ushort4*)(S_s + node * 128 + ((dd0 * 2) ^ ((node & 7) << 4))) = u;
            }
        }
        __syncthreads();

        // ---- matB: h'[node][dout]; wave wv owns node tiles 2wv,2wv+1 --------
        {
            bf16x8 wf[8];
            #pragma unroll
            for (int nt = 0; nt < 4; ++nt)
                #pragma unroll
                for (int kk = 0; kk < 2; ++kk) {
                    const float4* p = (const float4*)(W + (nt * 16 + l15) * NH
                                                      + kk * 32 + lg * 8);
                    float4 v0 = p[0], v1 = p[1];
                    bf16x8 a;
                    a[0] = (__bf16)v0.x; a[1] = (__bf16)v0.y; a[2] = (__bf16)v0.z; a[3] = (__bf16)v0.w;
                    a[4] = (__bf16)v1.x; a[5] = (__bf16)v1.y; a[6] = (__bf16)v1.z; a[7] = (__bf16)v1.w;
                    wf[nt * 2 + kk] = a;
                }
            f32x4 acc[2][4] = {};
            const int r0 = (wv * 2 + 0) * 16 + l15;
            const int r1 = (wv * 2 + 1) * 16 + l15;
            #pragma unroll
            for (int kk = 0; kk < 2; ++kk) {
                const int kb = kk * 64 + lg * 16;
                bf16x8 s0 = *(const bf16x8*)(S_s + r0 * 128 + (kb ^ ((r0 & 7) << 4)));
                bf16x8 s1 = *(const bf16x8*)(S_s + r1 * 128 + (kb ^ ((r1 & 7) << 4)));
                #pragma unroll
                for (int nt = 0; nt < 4; ++nt) {
                    acc[0][nt] = __builtin_amdgcn_mfma_f32_16x16x32_bf16(s0, wf[nt * 2 + kk], acc[0][nt], 0, 0, 0);
                    acc[1][nt] = __builtin_amdgcn_mfma_f32_16x16x32_bf16(s1, wf[nt * 2 + kk], acc[1][nt], 0, 0, 0);
                }
            }
            #pragma unroll
            for (int m = 0; m < 2; ++m)
                #pragma unroll
                for (int nt = 0; nt < 4; ++nt) {
                    int dout  = nt * 16 + l15;
                    int node0 = (wv * 2 + m) * 16 + lg * 4;
                    ushort4 u;
                    u.x = f2b(fmaxf(acc[m][nt][0], 0.f));
                    u.y = f2b(fmaxf(acc[m][nt][1], 0.f));
                    u.z = f2b(fmaxf(acc[m][nt][2], 0.f));
                    u.w = f2b(fmaxf(acc[m][nt][3], 0.f));
                    *(ushort4*)(hT_s + dout * 256 + ((node0 * 2) ^ ((dout & 7) << 4))) = u;
                }
        }
        __syncthreads();
    }

    // ---------------- layer 3: svec[d] = sum_node (adj @ h2)^T[d][node] ------
    {
        f32x4 acc[8] = {};
        const int arow = wv * 16 + l15;              // hT2 row (d)
        #pragma unroll
        for (int kk = 0; kk < 4; ++kk) {
            const int kb = kk * 64 + lg * 16;
            bf16x8 ha = *(const bf16x8*)(hT_s + arow * 256 + (kb ^ ((arow & 7) << 4)));
            bf16x8 bfr[8];
            #pragma unroll
            for (int nt = 0; nt < 8; ++nt) {
                int brow = nt * 16 + l15;
                bfr[nt] = *(const bf16x8*)(adj_s + brow * 256 + (kb ^ ((brow & 7) << 4)));
            }
            #pragma unroll
            for (int nt = 0; nt < 8; ++nt)
                acc[nt] = __builtin_amdgcn_mfma_f32_16x16x32_bf16(ha, bfr[nt], acc[nt], 0, 0, 0);
        }
        // sum the 8 node tiles (VALU), then 16 lanes within each lg group
        f32x4 s = ((acc[0] + acc[1]) + (acc[2] + acc[3]))
                + ((acc[4] + acc[5]) + (acc[6] + acc[7]));
        #pragma unroll
        for (int m = 1; m <= 8; m <<= 1) {
            s[0] += __shfl_xor(s[0], m);
            s[1] += __shfl_xor(s[1], m);
            s[2] += __shfl_xor(s[2], m);
            s[3] += __shfl_xor(s[3], m);
        }
        if (l15 == 0)
            *(f32x4*)(svec + wv * 16 + lg * 4) = s;   // d = wv*16 + lg*4 + i
    }
    __syncthreads();

    // ---------------- out[b][o] = sum_d W3[o][d] * svec[d] (fp32) ------------
    if (t < 128) {
        const float4* wrow = (const float4*)(W3 + t * NH);
        float a0 = 0.f, a1 = 0.f;
        #pragma unroll
        for (int q = 0; q < 16; q += 2) {
            float4 w0 = wrow[q], w1 = wrow[q + 1];
            a0 += w0.x*svec[q*4+0] + w0.y*svec[q*4+1] + w0.z*svec[q*4+2] + w0.w*svec[q*4+3];
            a1 += w1.x*svec[q*4+4] + w1.y*svec[q*4+5] + w1.z*svec[q*4+6] + w1.w*svec[q*4+7];
        }
        out[b * NOUT + t] = a0 + a1;
    }
}

extern "C" void kernel_launch(void* const* d_in, const int* in_sizes, int n_in,
                              void* d_out, int out_size, void* d_ws, size_t ws_size,
                              hipStream_t stream) {
    const int*   graph = (const int*)d_in[0];
    const float* adjp  = (const float*)d_in[1];
    const float* embed = (const float*)d_in[2];
    const float* W1    = (const float*)d_in[3];
    const float* W2    = (const float*)d_in[4];
    const float* W3    = (const float*)d_in[5];
    float* outp = (float*)d_out;

    rsgcn_fused<<<dim3(NB), dim3(256), 0, stream>>>(graph, adjp, embed, W1, W2, W3, outp);
}